// Round 1
// baseline (153.268 us; speedup 1.0000x reference)
//
#include <hip/hip_runtime.h>

typedef unsigned int uint;

#define K_SEL   13107u
#define BATCH   256
#define UNITS   131072
#define EQ_CAP  256

// ---------- workspace layout (bytes) ----------
// 0        boost   [UNITS] f32           524288
// 524288   ghist1  [256][2048] u32      2097152   (memset 0)
// 2621440  ghist2  [256][2048] u32      2097152   (memset 0)
// 4718592  ghist3  [256][1024] u32      1048576   (memset 0)
// 5767168  colcnt  [UNITS] u32           524288   (memset 0)
// 6291456  eqn     [256] u32               1024   (memset 0)
// 6292480  keypfx  [256] u32               1024
// 6293504  gt      [256] u32               1024
// 6294528  tkey    [256] u32               1024
// 6295552  need    [256] u32               1024
// 6296576  eqcnt   [256] u32               1024
// 6297600  eqidx   [256][EQ_CAP] u32     262144
// total ~6.26 MB

__device__ __forceinline__ uint tokey(float f) {
    uint b = __float_as_uint(f);
    return b ^ ((uint)((int)b >> 31) | 0x80000000u);
}

__global__ void boost_kernel(const float* __restrict__ duty, float* __restrict__ boost) {
    int u = blockIdx.x * 256 + threadIdx.x;
    const float TARGET = (float)(13107.0 / 131072.0);
    float t = __fsub_rn(TARGET, duty[u]);
    // double exp -> correctly-rounded f32 (match np.exp float32 as closely as possible)
    boost[u] = (float)exp((double)t);
}

template <int ROUND>
__global__ void hist_kernel(const float* __restrict__ in, const float* __restrict__ boost,
                            const uint* __restrict__ keypfx, uint* __restrict__ ghist,
                            int nbins) {
    __shared__ uint lh[4][2048];   // per-wave replicas to cut LDS atomic contention
    const int row = blockIdx.y;
    uint* h = lh[threadIdx.x >> 6];
    for (int i = threadIdx.x; i < 4 * 2048; i += 256) ((uint*)lh)[i] = 0u;
    __syncthreads();

    uint pfx = 0;
    if (ROUND != 1) pfx = keypfx[row];

    const float4* inp = (const float4*)(in + (size_t)row * UNITS) + (size_t)blockIdx.x * 4096;
    const float4* bst = (const float4*)boost + (size_t)blockIdx.x * 4096;

    for (int i = 0; i < 16; i++) {
        int idx = i * 256 + threadIdx.x;
        float4 a = inp[idx];
        float4 b = bst[idx];
        uint k0 = tokey(a.x * b.x);
        uint k1 = tokey(a.y * b.y);
        uint k2 = tokey(a.z * b.z);
        uint k3 = tokey(a.w * b.w);
        if (ROUND == 1) {
            atomicAdd(&h[k0 >> 21], 1u);
            atomicAdd(&h[k1 >> 21], 1u);
            atomicAdd(&h[k2 >> 21], 1u);
            atomicAdd(&h[k3 >> 21], 1u);
        } else if (ROUND == 2) {
            if ((k0 >> 21) == pfx) atomicAdd(&h[(k0 >> 10) & 2047u], 1u);
            if ((k1 >> 21) == pfx) atomicAdd(&h[(k1 >> 10) & 2047u], 1u);
            if ((k2 >> 21) == pfx) atomicAdd(&h[(k2 >> 10) & 2047u], 1u);
            if ((k3 >> 21) == pfx) atomicAdd(&h[(k3 >> 10) & 2047u], 1u);
        } else {
            if ((k0 >> 10) == pfx) atomicAdd(&h[k0 & 1023u], 1u);
            if ((k1 >> 10) == pfx) atomicAdd(&h[k1 & 1023u], 1u);
            if ((k2 >> 10) == pfx) atomicAdd(&h[k2 & 1023u], 1u);
            if ((k3 >> 10) == pfx) atomicAdd(&h[k3 & 1023u], 1u);
        }
    }
    __syncthreads();
    uint* gh = ghist + (size_t)row * nbins;
    for (int i = threadIdx.x; i < nbins; i += 256) {
        uint s = lh[0][i] + lh[1][i] + lh[2][i] + lh[3][i];
        if (s) atomicAdd(&gh[i], s);
    }
}

// Finds the bin containing the K-th largest (counting from the top), per row.
__global__ void scan_kernel(const uint* __restrict__ ghist, int nbins, int tseg, int round,
                            uint* __restrict__ keypfx, uint* __restrict__ gt,
                            uint* __restrict__ tkey, uint* __restrict__ need,
                            uint* __restrict__ eqcnt) {
    __shared__ uint h[2048];
    __shared__ uint ts[256];
    const int row = blockIdx.x;
    const int tid = threadIdx.x;
    const uint* hr = ghist + (size_t)row * nbins;
    for (int i = tid; i < nbins; i += 256) h[i] = hr[i];
    __syncthreads();

    const int b0 = tid * tseg;
    uint s = 0;
    for (int i = 0; i < tseg; i++) s += h[b0 + i];
    ts[tid] = s;
    __syncthreads();
    // inclusive suffix scan over thread sums
    for (int off = 1; off < 256; off <<= 1) {
        uint v = (tid + off < 256) ? ts[tid + off] : 0u;
        __syncthreads();
        ts[tid] += v;
        __syncthreads();
    }
    uint prior  = (round == 1) ? 0u : gt[row];
    uint pfxold = (round == 1) ? 0u : keypfx[row];
    __syncthreads();   // all reads of gt/keypfx done before any write below

    uint cum = ts[tid] - s + prior;   // count of elements strictly greater than top of my segment
    for (int i = tseg - 1; i >= 0; i--) {
        uint hb = h[b0 + i];
        uint c2 = cum + hb;
        if (cum < K_SEL && c2 >= K_SEL) {
            uint b = (uint)(b0 + i);
            if (round == 3) {
                tkey[row]  = (pfxold << 10) | b;
                need[row]  = K_SEL - cum;   // how many of the equal-key elements to take
                eqcnt[row] = hb;            // exact count of elements equal to tkey
            } else {
                keypfx[row] = (pfxold << 11) | b;
                gt[row]     = cum;
            }
        }
        cum = c2;
    }
}

// Only runs for rows with more equal-key elements than needed (ties at threshold).
__global__ void collect_kernel(const float* __restrict__ in, const float* __restrict__ boost,
                               const uint* __restrict__ tkey, const uint* __restrict__ need,
                               const uint* __restrict__ eqcnt, uint* __restrict__ eqn,
                               uint* __restrict__ eqidx) {
    const int row = blockIdx.y;
    if (eqcnt[row] <= need[row]) return;   // no tie to break
    const uint tk = tkey[row];
    const float4* inp = (const float4*)(in + (size_t)row * UNITS) + (size_t)blockIdx.x * 4096;
    const float4* bst = (const float4*)boost + (size_t)blockIdx.x * 4096;
    for (int i = 0; i < 16; i++) {
        int idx = i * 256 + threadIdx.x;
        float4 a = inp[idx];
        float4 b = bst[idx];
        uint ubase = blockIdx.x * 16384 + idx * 4;
        uint k0 = tokey(a.x * b.x);
        uint k1 = tokey(a.y * b.y);
        uint k2 = tokey(a.z * b.z);
        uint k3 = tokey(a.w * b.w);
        if (k0 == tk) { uint p = atomicAdd(&eqn[row], 1u); if (p < EQ_CAP) eqidx[row * EQ_CAP + p] = ubase + 0; }
        if (k1 == tk) { uint p = atomicAdd(&eqn[row], 1u); if (p < EQ_CAP) eqidx[row * EQ_CAP + p] = ubase + 1; }
        if (k2 == tk) { uint p = atomicAdd(&eqn[row], 1u); if (p < EQ_CAP) eqidx[row * EQ_CAP + p] = ubase + 2; }
        if (k3 == tk) { uint p = atomicAdd(&eqn[row], 1u); if (p < EQ_CAP) eqidx[row * EQ_CAP + p] = ubase + 3; }
    }
}

__global__ void apply_kernel(const float* __restrict__ in, const float* __restrict__ boost,
                             const uint* __restrict__ tkey, const uint* __restrict__ need,
                             const uint* __restrict__ eqcnt, const uint* __restrict__ eqn,
                             const uint* __restrict__ eqidx, float* __restrict__ out,
                             uint* __restrict__ colcnt) {
    __shared__ uint s_tk[64], s_need[64], s_eq[64], s_en[64];
    const int r0 = blockIdx.y * 64;
    if (threadIdx.x < 64) {
        int r = r0 + threadIdx.x;
        s_tk[threadIdx.x]   = tkey[r];
        s_need[threadIdx.x] = need[r];
        s_eq[threadIdx.x]   = eqcnt[r];
        s_en[threadIdx.x]   = eqn[r];
    }
    __syncthreads();
    const int u = blockIdx.x * 256 + threadIdx.x;
    const float bst = boost[u];
    uint cnt = 0;
    for (int r = 0; r < 64; r++) {
        const int row = r0 + r;
        const float v = in[(size_t)row * UNITS + u];
        const uint k = tokey(v * bst);
        const uint tk = s_tk[r];
        bool win;
        if (k > tk) {
            win = true;
        } else if (k == tk) {
            if (s_eq[r] <= s_need[r]) {
                win = true;                       // all equals taken (common case)
            } else {
                uint m = s_en[r]; if (m > (uint)EQ_CAP) m = EQ_CAP;
                const uint* el = eqidx + (size_t)row * EQ_CAP;
                uint rank = 0;
                for (uint j = 0; j < m; j++) rank += (el[j] < (uint)u) ? 1u : 0u;
                win = rank < s_need[r];           // lowest-index-first tie break
            }
        } else {
            win = false;
        }
        out[(size_t)row * UNITS + u] = win ? v : 0.0f;
        cnt += win ? 1u : 0u;
    }
    atomicAdd(&colcnt[u], cnt);
}

__global__ void duty_kernel(const float* __restrict__ duty, const uint* __restrict__ colcnt,
                            float* __restrict__ out_duty) {
    int u = blockIdx.x * 256 + threadIdx.x;
    const float C1 = (float)(1.0 - 1.0 / 1000.0);
    const float C2 = (float)(1.0 / 1000.0);
    float cur = (float)colcnt[u] * (1.0f / 256.0f);   // exact
    out_duty[u] = __fadd_rn(__fmul_rn(C1, duty[u]), __fmul_rn(C2, cur));
}

extern "C" void kernel_launch(void* const* d_in, const int* in_sizes, int n_in,
                              void* d_out, int out_size, void* d_ws, size_t ws_size,
                              hipStream_t stream) {
    const float* inputs = (const float*)d_in[0];
    const float* duty   = (const float*)d_in[1];
    float* out      = (float*)d_out;
    float* out_duty = out + (size_t)BATCH * UNITS;

    char* ws = (char*)d_ws;
    float* boost  = (float*)(ws + 0);
    uint* ghist1  = (uint*)(ws + 524288);
    uint* ghist2  = (uint*)(ws + 2621440);
    uint* ghist3  = (uint*)(ws + 4718592);
    uint* colcnt  = (uint*)(ws + 5767168);
    uint* eqn     = (uint*)(ws + 6291456);
    uint* keypfx  = (uint*)(ws + 6292480);
    uint* gt      = (uint*)(ws + 6293504);
    uint* tkey    = (uint*)(ws + 6294528);
    uint* need    = (uint*)(ws + 6295552);
    uint* eqcnt   = (uint*)(ws + 6296576);
    uint* eqidx   = (uint*)(ws + 6297600);

    // zero: ghist1, ghist2, ghist3, colcnt, eqn (contiguous)
    hipMemsetAsync(ws + 524288, 0, 5768192, stream);

    boost_kernel<<<UNITS / 256, 256, 0, stream>>>(duty, boost);

    hist_kernel<1><<<dim3(8, 256), 256, 0, stream>>>(inputs, boost, nullptr, ghist1, 2048);
    scan_kernel<<<256, 256, 0, stream>>>(ghist1, 2048, 8, 1, keypfx, gt, tkey, need, eqcnt);

    hist_kernel<2><<<dim3(8, 256), 256, 0, stream>>>(inputs, boost, keypfx, ghist2, 2048);
    scan_kernel<<<256, 256, 0, stream>>>(ghist2, 2048, 8, 2, keypfx, gt, tkey, need, eqcnt);

    hist_kernel<3><<<dim3(8, 256), 256, 0, stream>>>(inputs, boost, keypfx, ghist3, 1024);
    scan_kernel<<<256, 256, 0, stream>>>(ghist3, 1024, 4, 3, keypfx, gt, tkey, need, eqcnt);

    collect_kernel<<<dim3(8, 256), 256, 0, stream>>>(inputs, boost, tkey, need, eqcnt, eqn, eqidx);

    apply_kernel<<<dim3(UNITS / 256, 4), 256, 0, stream>>>(inputs, boost, tkey, need, eqcnt,
                                                           eqn, eqidx, out, colcnt);

    duty_kernel<<<UNITS / 256, 256, 0, stream>>>(duty, colcnt, out_duty);
}

// Round 2
// 134.738 us; speedup vs baseline: 1.1375x; 1.1375x over previous
//
#include <hip/hip_runtime.h>

typedef unsigned int uint;

#define K_SEL   13107u
#define BATCH   256
#define UNITS   131072
#define EQ_CAP  1024
#define RS_T    1024

// ---------- workspace layout (bytes) ----------
// 0        boost   [131072] f32          524288
// 524288   tkey    [256] u32               1024
// 525312   need    [256] u32               1024
// 526336   eqcnt   [256] u32               1024
// 527360   eqn     [256] u32               1024
// 528384   eqidx   [256][EQ_CAP] u32    1048576
// 1576960  cnt4    [4][131072] u32      2097152
// total 3674112 bytes (~3.5 MB); no memset required anywhere.

__device__ __forceinline__ uint tokey(float f) {
    uint b = __float_as_uint(f);
    return b ^ ((uint)((int)b >> 31) | 0x80000000u);
}

__global__ void boost_kernel(const float* __restrict__ duty, float* __restrict__ boost) {
    int u = blockIdx.x * 256 + threadIdx.x;
    const float TARGET = (float)(13107.0 / 131072.0);
    float t = __fsub_rn(TARGET, duty[u]);
    // double exp -> correctly-rounded f32 (matches np.exp float32)
    boost[u] = (float)exp((double)t);
}

// One block per row: full 3-round radix select + tie collection, row stays in L2.
__global__ __launch_bounds__(RS_T) void rowselect_kernel(
    const float* __restrict__ in, const float* __restrict__ boost,
    uint* __restrict__ tkey_a, uint* __restrict__ need_a,
    uint* __restrict__ eqcnt_a, uint* __restrict__ eqn_a,
    uint* __restrict__ eqidx) {
    __shared__ uint hist[8 * 2049];   // 8 padded replicas (bank-rotated)
    __shared__ uint ts[RS_T];
    __shared__ uint bc[3];            // crossing: {bin, cum_gt, bin_count}
    __shared__ uint eqn_s;

    const int row = blockIdx.x;
    const int tid = threadIdx.x;
    uint* h = &hist[((tid >> 6) & 7) * 2049];
    const float4* inp = (const float4*)(in + (size_t)row * UNITS);
    const float4* bst = (const float4*)boost;

    uint pfx = 0;     // matched key prefix so far
    uint prior = 0;   // count of keys strictly greater than current prefix range

    for (int round = 0; round < 3; ++round) {
        const int nbins = (round == 2) ? 1024 : 2048;
        for (int i = tid; i < 8 * 2049; i += RS_T) hist[i] = 0u;
        __syncthreads();

        for (int i = tid; i < UNITS / 4; i += RS_T) {
            float4 a = inp[i];
            float4 b = bst[i];
            uint k0 = tokey(a.x * b.x);
            uint k1 = tokey(a.y * b.y);
            uint k2 = tokey(a.z * b.z);
            uint k3 = tokey(a.w * b.w);
            if (round == 0) {
                atomicAdd(&h[k0 >> 21], 1u);
                atomicAdd(&h[k1 >> 21], 1u);
                atomicAdd(&h[k2 >> 21], 1u);
                atomicAdd(&h[k3 >> 21], 1u);
            } else if (round == 1) {
                if ((k0 >> 21) == pfx) atomicAdd(&h[(k0 >> 10) & 2047u], 1u);
                if ((k1 >> 21) == pfx) atomicAdd(&h[(k1 >> 10) & 2047u], 1u);
                if ((k2 >> 21) == pfx) atomicAdd(&h[(k2 >> 10) & 2047u], 1u);
                if ((k3 >> 21) == pfx) atomicAdd(&h[(k3 >> 10) & 2047u], 1u);
            } else {
                if ((k0 >> 10) == pfx) atomicAdd(&h[k0 & 1023u], 1u);
                if ((k1 >> 10) == pfx) atomicAdd(&h[k1 & 1023u], 1u);
                if ((k2 >> 10) == pfx) atomicAdd(&h[k2 & 1023u], 1u);
                if ((k3 >> 10) == pfx) atomicAdd(&h[k3 & 1023u], 1u);
            }
        }
        __syncthreads();

        // replica-sum + in-block suffix scan
        const int tseg = nbins / RS_T;          // 2 (rounds 0,1) or 1 (round 2)
        const int b0 = tid * tseg;
        uint binsum[2];
        uint segsum = 0;
        for (int i = 0; i < tseg; i++) {
            uint s = 0;
            for (int r = 0; r < 8; r++) s += hist[r * 2049 + b0 + i];
            binsum[i] = s;
            segsum += s;
        }
        ts[tid] = segsum;
        __syncthreads();
        for (int off = 1; off < RS_T; off <<= 1) {
            uint v = (tid + off < RS_T) ? ts[tid + off] : 0u;
            __syncthreads();
            ts[tid] += v;
            __syncthreads();
        }
        uint cum = ts[tid] - segsum + prior;    // strictly-greater count above my segment
        for (int i = tseg - 1; i >= 0; i--) {
            uint hb = binsum[i];
            uint c2 = cum + hb;
            if (cum < K_SEL && c2 >= K_SEL) {
                bc[0] = (uint)(b0 + i);
                bc[1] = cum;
                bc[2] = hb;
            }
            cum = c2;
        }
        __syncthreads();
        uint b = bc[0];
        prior = bc[1];
        if (round == 0)      pfx = b;
        else if (round == 1) pfx = (pfx << 11) | b;
        else                 pfx = (pfx << 10) | b;
        if (round == 2 && tid == 0) {
            tkey_a[row]  = pfx;
            need_a[row]  = K_SEL - prior;
            eqcnt_a[row] = bc[2];
            eqn_s = 0u;
        }
        __syncthreads();
    }

    const uint tkey  = pfx;
    const uint need  = K_SEL - prior;
    const uint eqcnt = bc[2];

    if (eqcnt > need) {
        // ties at the exact threshold key: collect their indices (rank-by-index later)
        for (int i = tid; i < UNITS / 4; i += RS_T) {
            float4 a = inp[i];
            float4 b = bst[i];
            uint base = (uint)i * 4u;
            uint k0 = tokey(a.x * b.x);
            uint k1 = tokey(a.y * b.y);
            uint k2 = tokey(a.z * b.z);
            uint k3 = tokey(a.w * b.w);
            if (k0 == tkey) { uint p = atomicAdd(&eqn_s, 1u); if (p < EQ_CAP) eqidx[(size_t)row * EQ_CAP + p] = base + 0; }
            if (k1 == tkey) { uint p = atomicAdd(&eqn_s, 1u); if (p < EQ_CAP) eqidx[(size_t)row * EQ_CAP + p] = base + 1; }
            if (k2 == tkey) { uint p = atomicAdd(&eqn_s, 1u); if (p < EQ_CAP) eqidx[(size_t)row * EQ_CAP + p] = base + 2; }
            if (k3 == tkey) { uint p = atomicAdd(&eqn_s, 1u); if (p < EQ_CAP) eqidx[(size_t)row * EQ_CAP + p] = base + 3; }
        }
        __syncthreads();
        if (tid == 0) eqn_a[row] = eqn_s;
    } else if (tid == 0) {
        eqn_a[row] = 0u;
    }
}

__global__ void apply_kernel(const float* __restrict__ in, const float* __restrict__ boost,
                             const uint* __restrict__ tkey, const uint* __restrict__ need,
                             const uint* __restrict__ eqcnt, const uint* __restrict__ eqn,
                             const uint* __restrict__ eqidx, float* __restrict__ out,
                             uint* __restrict__ cnt4) {
    __shared__ uint s_tk[64], s_need[64], s_eq[64], s_en[64];
    const int r0 = blockIdx.y * 64;
    if (threadIdx.x < 64) {
        int r = r0 + threadIdx.x;
        s_tk[threadIdx.x]   = tkey[r];
        s_need[threadIdx.x] = need[r];
        s_eq[threadIdx.x]   = eqcnt[r];
        s_en[threadIdx.x]   = eqn[r];
    }
    __syncthreads();

    const int c4 = blockIdx.x * 256 + threadIdx.x;   // float4 column index
    const float4 bst = ((const float4*)boost)[c4];
    const uint u0 = (uint)c4 * 4u;
    uint cnt[4] = {0u, 0u, 0u, 0u};

    for (int r = 0; r < 64; r++) {
        const int row = r0 + r;
        const float4 v = ((const float4*)(in + (size_t)row * UNITS))[c4];
        const uint tk = s_tk[r];
        const uint nd = s_need[r];
        const bool all_eq = (s_eq[r] <= nd);
        float o[4];
        const float vv[4] = {v.x, v.y, v.z, v.w};
        const float bb[4] = {bst.x, bst.y, bst.z, bst.w};
        #pragma unroll
        for (int c = 0; c < 4; c++) {
            const uint k = tokey(vv[c] * bb[c]);
            bool win;
            if (k > tk) {
                win = true;
            } else if (k == tk) {
                if (all_eq) {
                    win = true;
                } else {
                    uint m = s_en[r]; if (m > (uint)EQ_CAP) m = EQ_CAP;
                    const uint* el = eqidx + (size_t)row * EQ_CAP;
                    const uint u = u0 + (uint)c;
                    uint rank = 0;
                    for (uint j = 0; j < m; j++) rank += (el[j] < u) ? 1u : 0u;
                    win = rank < nd;              // lowest-index-first tie break
                }
            } else {
                win = false;
            }
            o[c] = win ? vv[c] : 0.0f;
            cnt[c] += win ? 1u : 0u;
        }
        float4 ov = make_float4(o[0], o[1], o[2], o[3]);
        ((float4*)(out + (size_t)row * UNITS))[c4] = ov;
    }
    uint4 cv = make_uint4(cnt[0], cnt[1], cnt[2], cnt[3]);
    ((uint4*)(cnt4 + (size_t)blockIdx.y * UNITS))[c4] = cv;
}

__global__ void duty_kernel(const float* __restrict__ duty, const uint* __restrict__ cnt4,
                            float* __restrict__ out_duty) {
    int u = blockIdx.x * 256 + threadIdx.x;
    const float C1 = (float)(1.0 - 1.0 / 1000.0);
    const float C2 = (float)(1.0 / 1000.0);
    uint c = cnt4[u] + cnt4[UNITS + u] + cnt4[2 * UNITS + u] + cnt4[3 * UNITS + u];
    float cur = (float)c * (1.0f / 256.0f);   // exact
    out_duty[u] = __fadd_rn(__fmul_rn(C1, duty[u]), __fmul_rn(C2, cur));
}

extern "C" void kernel_launch(void* const* d_in, const int* in_sizes, int n_in,
                              void* d_out, int out_size, void* d_ws, size_t ws_size,
                              hipStream_t stream) {
    const float* inputs = (const float*)d_in[0];
    const float* duty   = (const float*)d_in[1];
    float* out      = (float*)d_out;
    float* out_duty = out + (size_t)BATCH * UNITS;

    char* ws = (char*)d_ws;
    float* boost = (float*)(ws + 0);
    uint* tkey   = (uint*)(ws + 524288);
    uint* need   = (uint*)(ws + 525312);
    uint* eqcnt  = (uint*)(ws + 526336);
    uint* eqn    = (uint*)(ws + 527360);
    uint* eqidx  = (uint*)(ws + 528384);
    uint* cnt4   = (uint*)(ws + 1576960);

    boost_kernel<<<UNITS / 256, 256, 0, stream>>>(duty, boost);

    rowselect_kernel<<<BATCH, RS_T, 0, stream>>>(inputs, boost, tkey, need, eqcnt, eqn, eqidx);

    apply_kernel<<<dim3(UNITS / 1024, 4), 256, 0, stream>>>(inputs, boost, tkey, need, eqcnt,
                                                            eqn, eqidx, out, cnt4);

    duty_kernel<<<UNITS / 256, 256, 0, stream>>>(duty, cnt4, out_duty);
}